// Round 14
// baseline (151.485 us; speedup 1.0000x reference)
//
#include <hip/hip_runtime.h>
#include <hip/hip_bf16.h>

typedef float floatx4 __attribute__((ext_vector_type(4)));
typedef float floatx16 __attribute__((ext_vector_type(16)));
typedef short short8 __attribute__((ext_vector_type(8)));
typedef unsigned int uintx4 __attribute__((ext_vector_type(4)));

#define S_LEN 4096
#define D_DIM 1024
#define NHEAD 16
#define SCALE_LOG2 0.1803368801111204f  /* 1/sqrt(64) * log2(e) */

__device__ __forceinline__ void gload_lds16(const void* g, void* l) {
  __builtin_amdgcn_global_load_lds(
      (const __attribute__((address_space(1))) unsigned int*)g,
      (__attribute__((address_space(3))) unsigned int*)l, 16, 0, 0);
}

__device__ __forceinline__ unsigned short f2bf_bits(float f) {
  __hip_bfloat16 h = __float2bfloat16(f);
  return __builtin_bit_cast(unsigned short, h);
}

// One launch converts input x (blocks 0..4095) and the 4 weights (4096..8191).
__global__ __launch_bounds__(256) void cvt_all(const float* __restrict__ x,
                                               const float* __restrict__ w0,
                                               const float* __restrict__ w1,
                                               const float* __restrict__ w2,
                                               const float* __restrict__ w3,
                                               unsigned short* __restrict__ xo,
                                               unsigned short* __restrict__ o0,
                                               unsigned short* __restrict__ o1,
                                               unsigned short* __restrict__ o2,
                                               unsigned short* __restrict__ o3) {
  const int bid = blockIdx.x;
  const float* in;
  unsigned short* out;
  int i;
  if (bid < 4096) {
    in = x;
    out = xo;
    i = bid * 256 + threadIdx.x;
  } else {
    const int which = (bid - 4096) >> 10;
    in = which == 0 ? w0 : which == 1 ? w1 : which == 2 ? w2 : w3;
    out = which == 0 ? o0 : which == 1 ? o1 : which == 2 ? o2 : o3;
    i = ((bid - 4096) & 1023) * 256 + threadIdx.x;
  }
  float4 v = reinterpret_cast<const float4*>(in)[i];
  ushort4 u;
  u.x = f2bf_bits(v.x);
  u.y = f2bf_bits(v.y);
  u.z = f2bf_bits(v.z);
  u.w = f2bf_bits(v.w);
  reinterpret_cast<ushort4*>(out)[i] = u;
}

// Fused QKV projection, BK=32, double-buffered LDS, one barrier per K-step.
__global__ __launch_bounds__(256) void gemm_qkv(const unsigned short* __restrict__ A,
                                                const unsigned short* __restrict__ WqB,
                                                const unsigned short* __restrict__ WkB,
                                                const unsigned short* __restrict__ WvB,
                                                const float* __restrict__ bq,
                                                const float* __restrict__ bk,
                                                const float* __restrict__ bv,
                                                unsigned short* __restrict__ Qo,
                                                unsigned short* __restrict__ Ko,
                                                unsigned short* __restrict__ VTo) {
  __shared__ __align__(16) unsigned short As[2][128 * 32];
  __shared__ __align__(16) unsigned short Bs[2][128 * 32];
  const int K = 1024, N = 1024, M = 4096;
  const int tid = threadIdx.x;
  const int wave = tid >> 6, lane = tid & 63;
  const int seg = blockIdx.y >> 3;
  const int m0 = blockIdx.x * 128, n0 = (blockIdx.y & 7) * 128;
  const unsigned short* B = seg == 0 ? WqB : seg == 1 ? WkB : WvB;
  const float* bias = seg == 0 ? bq : seg == 1 ? bk : bv;
  const int wr = wave >> 1, wc = wave & 1;

  floatx4 acc[4][4] = {};
  const unsigned short* Ab = A + (size_t)m0 * K;
  const unsigned short* Bb = B + (size_t)n0 * K;
  const int srow = lane >> 2, scol = (lane & 3) * 8;
  const int aRow = lane & 15, kOff = (lane >> 4) * 8;

  auto stage = [&](int buf, int k0) {
#pragma unroll
    for (int i = 0; i < 2; ++i) {
      const int c = wave * 2 + i;
      const int row = c * 16 + srow;
      gload_lds16(Ab + (size_t)row * K + k0 + scol, &As[buf][c * 512]);
      gload_lds16(Bb + (size_t)row * K + k0 + scol, &Bs[buf][c * 512]);
    }
  };

  stage(0, 0);
  int buf = 0;
  for (int k0 = 0; k0 < K; k0 += 32, buf ^= 1) {
    asm volatile("s_waitcnt vmcnt(0)" ::: "memory");
    __builtin_amdgcn_s_barrier();
    if (k0 + 32 < K) stage(buf ^ 1, k0 + 32);
    short8 af[4], bfg[4];
#pragma unroll
    for (int f = 0; f < 4; ++f) {
      af[f] =
          *reinterpret_cast<const short8*>(&As[buf][(wr * 64 + f * 16 + aRow) * 32 + kOff]);
      bfg[f] =
          *reinterpret_cast<const short8*>(&Bs[buf][(wc * 64 + f * 16 + aRow) * 32 + kOff]);
    }
#pragma unroll
    for (int fm = 0; fm < 4; ++fm)
#pragma unroll
      for (int fn = 0; fn < 4; ++fn)
        acc[fm][fn] =
            __builtin_amdgcn_mfma_f32_16x16x32_bf16(af[fm], bfg[fn], acc[fm][fn], 0, 0, 0);
  }

  const int rb = (lane >> 4) * 4, cl = lane & 15;
  const float osc = seg == 0 ? SCALE_LOG2 : 1.0f;
#pragma unroll
  for (int fm = 0; fm < 4; ++fm)
#pragma unroll
    for (int fn = 0; fn < 4; ++fn)
#pragma unroll
      for (int r = 0; r < 4; ++r) {
        const int row = m0 + wr * 64 + fm * 16 + rb + r;
        const int col = n0 + wc * 64 + fn * 16 + cl;
        const float v = (acc[fm][fn][r] + bias[col]) * osc;
        if (seg == 0)
          Qo[(size_t)row * N + col] = f2bf_bits(v);
        else if (seg == 1)
          Ko[(size_t)row * N + col] = f2bf_bits(v);
        else
          VTo[(size_t)col * M + row] = f2bf_bits(v);
      }
}

// O-projection, BK=32, double-buffered LDS, one barrier per K-step.
__global__ __launch_bounds__(256) void gemm_o(const unsigned short* __restrict__ A,
                                              const unsigned short* __restrict__ B,
                                              const float* __restrict__ bias,
                                              const float* __restrict__ resid,
                                              float* __restrict__ C) {
  __shared__ __align__(16) unsigned short As[2][64 * 32];
  __shared__ __align__(16) unsigned short Bs[2][128 * 32];
  const int K = 1024, N = 1024;
  const int tid = threadIdx.x;
  const int wave = tid >> 6, lane = tid & 63;
  const int m0 = blockIdx.x * 64, n0 = blockIdx.y * 128;
  const int wr = wave >> 1, wc = wave & 1;

  floatx4 acc[2][4] = {};
  const unsigned short* Ab = A + (size_t)m0 * K;
  const unsigned short* Bb = B + (size_t)n0 * K;
  const int srow = lane >> 2, scol = (lane & 3) * 8;
  const int aRow = lane & 15, kOff = (lane >> 4) * 8;

  auto stage = [&](int buf, int k0) {
#pragma unroll
    for (int i = 0; i < 3; ++i) {
      const int ci = wave * 3 + i;
      if (ci < 4) {
        const int row = ci * 16 + srow;
        gload_lds16(Ab + (size_t)row * K + k0 + scol, &As[buf][ci * 512]);
      } else {
        const int row = (ci - 4) * 16 + srow;
        gload_lds16(Bb + (size_t)row * K + k0 + scol, &Bs[buf][(ci - 4) * 512]);
      }
    }
  };

  stage(0, 0);
  int buf = 0;
  for (int k0 = 0; k0 < K; k0 += 32, buf ^= 1) {
    asm volatile("s_waitcnt vmcnt(0)" ::: "memory");
    __builtin_amdgcn_s_barrier();
    if (k0 + 32 < K) stage(buf ^ 1, k0 + 32);
    short8 af[2], bfg[4];
#pragma unroll
    for (int f = 0; f < 2; ++f)
      af[f] =
          *reinterpret_cast<const short8*>(&As[buf][(wr * 32 + f * 16 + aRow) * 32 + kOff]);
#pragma unroll
    for (int f = 0; f < 4; ++f)
      bfg[f] =
          *reinterpret_cast<const short8*>(&Bs[buf][(wc * 64 + f * 16 + aRow) * 32 + kOff]);
#pragma unroll
    for (int fm = 0; fm < 2; ++fm)
#pragma unroll
      for (int fn = 0; fn < 4; ++fn)
        acc[fm][fn] =
            __builtin_amdgcn_mfma_f32_16x16x32_bf16(af[fm], bfg[fn], acc[fm][fn], 0, 0, 0);
  }

  const int rb = (lane >> 4) * 4, cl = lane & 15;
#pragma unroll
  for (int fm = 0; fm < 2; ++fm)
#pragma unroll
    for (int fn = 0; fn < 4; ++fn)
#pragma unroll
      for (int r = 0; r < 4; ++r) {
        const int row = m0 + wr * 32 + fm * 16 + rb + r;
        const int col = n0 + wc * 64 + fn * 16 + cl;
        C[(size_t)row * N + col] =
            acc[fm][fn][r] + bias[col] + resid[(size_t)row * N + col];
      }
}

// Causal flash attention, 32x32 MFMA quadrant structure, single barrier/tile.
// Wave w: kb=w&1 (kv half), qb=w>>1 (q half).  QK^T swapped: C[kv][q],
// q = lane&31 lane-local, fixed-m softmax (log2 domain).  P kept in REGISTERS:
// C-layout -> B-frag layout via 4x v_permlane32_swap_b32 (no P LDS roundtrip).
// PV accumulates kv-half partials; cross-kb combine once per block via LDS
// scratch (reuses Ks).  1024 blocks heaviest-first; LDS 33KB.
__global__ __launch_bounds__(256) void attn_fwd(const unsigned short* __restrict__ Q,
                                                const unsigned short* __restrict__ Kg,
                                                const unsigned short* __restrict__ VT,
                                                unsigned short* __restrict__ O) {
  __shared__ __align__(16) unsigned short Ks[2 * 64 * 64];  // [buf][kv][d] swizzled
  __shared__ __align__(16) unsigned short Vs[2 * 64 * 64];  // [buf][d][kv] swizzled
  __shared__ float Lred[64];

  const int bid = blockIdx.x;
  const int h = bid & 15;
  const int qt = 63 - (bid >> 4);  // heaviest-first
  const int q0 = qt * 64;
  const int wave = threadIdx.x >> 6, lane = threadIdx.x & 63;
  const int l31 = lane & 31, hh = lane >> 5;
  const int kb = wave & 1, qb = wave >> 1;
  const int sw7 = l31 & 7;  // chunk-XOR key (row & 7)

  const int qrow = q0 + qb * 32 + l31;  // this lane's q-row
  short8 qf[4];
#pragma unroll
  for (int s = 0; s < 4; ++s)
    qf[s] = *reinterpret_cast<const short8*>(
        &Q[(size_t)qrow * D_DIM + h * 64 + s * 16 + hh * 8]);

  floatx16 acco0 = {}, acco1 = {};  // db=0 / db=1 partials over this wave's kv half
  float l_run = 0.f;
  unsigned pfw[8];  // loop-carried P B-frags (2 K-steps x 4 words)

  auto stageK = [&](int buf, int t) {
    const int kv0 = t * 64;
#pragma unroll
    for (int i = 0; i < 2; ++i) {
      const int seg = wave * 2 + i;
      const int c = seg * 64 + lane;
      const int r = c >> 3, jj = c & 7;
      const int sj = (jj ^ (r & 7)) * 8;
      gload_lds16(&Kg[(size_t)(kv0 + r) * D_DIM + h * 64 + sj],
                  &Ks[buf * 4096 + seg * 512]);
    }
  };
  auto stageV = [&](int buf, int t) {
    const int kv0 = t * 64;
#pragma unroll
    for (int i = 0; i < 2; ++i) {
      const int seg = wave * 2 + i;
      const int c = seg * 64 + lane;
      const int r = c >> 3, jj = c & 7;
      const int sj = (jj ^ (r & 7)) * 8;
      gload_lds16(&VT[(size_t)(h * 64 + r) * S_LEN + kv0 + sj],
                  &Vs[buf * 4096 + seg * 512]);
    }
  };

  // per-wave fragment addresses (tile-invariant)
  const int Rk = kb * 32 + l31;  // K-frag row
  int kaddr[4];
#pragma unroll
  for (int s = 0; s < 4; ++s) kaddr[s] = Rk * 64 + (((2 * s + hh) ^ sw7) * 8);
  int vaddr0[2], vaddr1[2];  // [ks] for db=0 / db=1
#pragma unroll
  for (int ks = 0; ks < 2; ++ks) {
    vaddr0[ks] = (0 * 32 + l31) * 64 + (((4 * kb + 2 * ks + hh) ^ sw7) * 8);
    vaddr1[ks] = (1 * 32 + l31) * 64 + (((4 * kb + 2 * ks + hh) ^ sw7) * 8);
  }

  auto do_pv = [&](const unsigned short* vsb) {
    uintx4 u0, u1;
    u0.x = pfw[0]; u0.y = pfw[1]; u0.z = pfw[2]; u0.w = pfw[3];
    u1.x = pfw[4]; u1.y = pfw[5]; u1.z = pfw[6]; u1.w = pfw[7];
    const short8 pf0 = __builtin_bit_cast(short8, u0);
    const short8 pf1 = __builtin_bit_cast(short8, u1);
    {
      const short8 vf00 = *reinterpret_cast<const short8*>(&vsb[vaddr0[0]]);
      acco0 = __builtin_amdgcn_mfma_f32_32x32x16_bf16(vf00, pf0, acco0, 0, 0, 0);
      const short8 vf01 = *reinterpret_cast<const short8*>(&vsb[vaddr0[1]]);
      acco0 = __builtin_amdgcn_mfma_f32_32x32x16_bf16(vf01, pf1, acco0, 0, 0, 0);
      const short8 vf10 = *reinterpret_cast<const short8*>(&vsb[vaddr1[0]]);
      acco1 = __builtin_amdgcn_mfma_f32_32x32x16_bf16(vf10, pf0, acco1, 0, 0, 0);
      const short8 vf11 = *reinterpret_cast<const short8*>(&vsb[vaddr1[1]]);
      acco1 = __builtin_amdgcn_mfma_f32_32x32x16_bf16(vf11, pf1, acco1, 0, 0, 0);
    }
  };

  const int ntiles = qt + 1;
  stageK(0, 0);

  for (int t = 0; t < ntiles; ++t) {
    asm volatile("s_waitcnt vmcnt(0)" ::: "memory");
    __builtin_amdgcn_s_barrier();
    if (t + 1 < ntiles) stageK((t + 1) & 1, t + 1);
    stageV(t & 1, t);

    const unsigned short* ksb = &Ks[(t & 1) * 4096];

    // S^T quadrant = K Q^T : C[kv][q], kv = kv0+kb*32+rowf, q = qrow
    floatx16 accs = {};
#pragma unroll
    for (int s = 0; s < 4; ++s) {
      const short8 kf = *reinterpret_cast<const short8*>(&ksb[kaddr[s]]);
      accs = __builtin_amdgcn_mfma_f32_32x32x16_bf16(kf, qf[s], accs, 0, 0, 0);
    }

    // PV(t-1) from saved register P-frags
    if (t > 0) do_pv(&Vs[((t - 1) & 1) * 4096]);

    // fixed-m softmax: P = exp2(score); diag tile masked -> 0
    const int kv0 = t * 64;
    float p[16];
    if (t == ntiles - 1) {
#pragma unroll
      for (int reg = 0; reg < 16; ++reg) {
        const int ka = kv0 + kb * 32 + (reg & 3) + 8 * (reg >> 2) + 4 * hh;
        const float s = (ka > qrow) ? -1e30f : accs[reg];
        p[reg] = __builtin_amdgcn_exp2f(s);
      }
    } else {
#pragma unroll
      for (int reg = 0; reg < 16; ++reg) p[reg] = __builtin_amdgcn_exp2f(accs[reg]);
    }
    float rs = 0.f;
#pragma unroll
    for (int reg = 0; reg < 16; ++reg) rs += p[reg];
    l_run += rs;

    // pack to bf16 pairs, then permlane32_swap -> B-frag layout (in-register)
    {
      unsigned w0 = (unsigned)f2bf_bits(p[0]) | ((unsigned)f2bf_bits(p[1]) << 16);
      unsigned w1 = (unsigned)f2bf_bits(p[2]) | ((unsigned)f2bf_bits(p[3]) << 16);
      unsigned w2 = (unsigned)f2bf_bits(p[4]) | ((unsigned)f2bf_bits(p[5]) << 16);
      unsigned w3 = (unsigned)f2bf_bits(p[6]) | ((unsigned)f2bf_bits(p[7]) << 16);
      unsigned w4 = (unsigned)f2bf_bits(p[8]) | ((unsigned)f2bf_bits(p[9]) << 16);
      unsigned w5 = (unsigned)f2bf_bits(p[10]) | ((unsigned)f2bf_bits(p[11]) << 16);
      unsigned w6 = (unsigned)f2bf_bits(p[12]) | ((unsigned)f2bf_bits(p[13]) << 16);
      unsigned w7 = (unsigned)f2bf_bits(p[14]) | ((unsigned)f2bf_bits(p[15]) << 16);
      asm volatile("v_permlane32_swap_b32 %0, %1" : "+v"(w0), "+v"(w2));
      asm volatile("v_permlane32_swap_b32 %0, %1" : "+v"(w1), "+v"(w3));
      asm volatile("v_permlane32_swap_b32 %0, %1" : "+v"(w4), "+v"(w6));
      asm volatile("v_permlane32_swap_b32 %0, %1" : "+v"(w5), "+v"(w7));
      pfw[0] = w0; pfw[1] = w1; pfw[2] = w2; pfw[3] = w3;
      pfw[4] = w4; pfw[5] = w5; pfw[6] = w6; pfw[7] = w7;
    }
  }

  // epilogue: PV(last)
  asm volatile("s_waitcnt vmcnt(0)" ::: "memory");
  __builtin_amdgcn_s_barrier();
  do_pv(&Vs[((ntiles - 1) & 1) * 4096]);

  l_run += __shfl_xor(l_run, 32);  // lanes l, l+32 share q

  __syncthreads();
  float* scr = reinterpret_cast<float*>(Ks);  // 16KB scratch (Ks no longer read)
  if (kb == 1) {
#pragma unroll
    for (int reg = 0; reg < 16; ++reg) {
      const int row = (reg & 3) + 8 * (reg >> 2) + 4 * hh;
      scr[(qb * 2 + 0) * 1024 + row * 32 + l31] = acco0[reg];
      scr[(qb * 2 + 1) * 1024 + row * 32 + l31] = acco1[reg];
    }
    if (lane < 32) Lred[qb * 32 + l31] = l_run;
  }
  __syncthreads();
  if (kb == 0) {
    const float inv = 1.f / (l_run + Lred[qb * 32 + l31]);
#pragma unroll
    for (int reg8 = 0; reg8 < 8; ++reg8) {
      const int ra = 2 * reg8, rb2 = 2 * reg8 + 1;
      const int rowa = (ra & 3) + 8 * (ra >> 2) + 4 * hh;  // rowb = rowa+1
      {
        const float va = (acco0[ra] + scr[(qb * 2 + 0) * 1024 + rowa * 32 + l31]) * inv;
        const float vb =
            (acco0[rb2] + scr[(qb * 2 + 0) * 1024 + (rowa + 1) * 32 + l31]) * inv;
        const unsigned pk = (unsigned)f2bf_bits(va) | ((unsigned)f2bf_bits(vb) << 16);
        *reinterpret_cast<unsigned*>(&O[(size_t)qrow * D_DIM + h * 64 + 0 + rowa]) = pk;
      }
      {
        const float va = (acco1[ra] + scr[(qb * 2 + 1) * 1024 + rowa * 32 + l31]) * inv;
        const float vb =
            (acco1[rb2] + scr[(qb * 2 + 1) * 1024 + (rowa + 1) * 32 + l31]) * inv;
        const unsigned pk = (unsigned)f2bf_bits(va) | ((unsigned)f2bf_bits(vb) << 16);
        *reinterpret_cast<unsigned*>(&O[(size_t)qrow * D_DIM + h * 64 + 32 + rowa]) = pk;
      }
    }
  }
}

__global__ __launch_bounds__(256) void ln_kernel(const float* __restrict__ X,
                                                 const float* __restrict__ g,
                                                 const float* __restrict__ b,
                                                 float* __restrict__ Y) {
  const int row = blockIdx.x;
  const int t = threadIdx.x;
  const float4 xv = reinterpret_cast<const float4*>(X + (size_t)row * 1024)[t];
  float s = xv.x + xv.y + xv.z + xv.w;
  float s2 = xv.x * xv.x + xv.y * xv.y + xv.z * xv.z + xv.w * xv.w;
#pragma unroll
  for (int off = 1; off < 64; off <<= 1) {
    s += __shfl_xor(s, off);
    s2 += __shfl_xor(s2, off);
  }
  __shared__ float sr[4], sr2[4];
  const int wave = t >> 6, lane = t & 63;
  if (lane == 0) {
    sr[wave] = s;
    sr2[wave] = s2;
  }
  __syncthreads();
  const float S = sr[0] + sr[1] + sr[2] + sr[3];
  const float S2 = sr2[0] + sr2[1] + sr2[2] + sr2[3];
  const float mu = S * (1.f / 1024.f);
  const float var = S2 * (1.f / 1024.f) - mu * mu;
  const float rstd = rsqrtf(var + 1e-5f);
  const float4 gv = reinterpret_cast<const float4*>(g)[t];
  const float4 bv = reinterpret_cast<const float4*>(b)[t];
  float4 y;
  y.x = (xv.x - mu) * rstd * gv.x + bv.x;
  y.y = (xv.y - mu) * rstd * gv.y + bv.y;
  y.z = (xv.z - mu) * rstd * gv.z + bv.z;
  y.w = (xv.w - mu) * rstd * gv.w + bv.w;
  reinterpret_cast<float4*>(Y + (size_t)row * 1024)[t] = y;
}

extern "C" void kernel_launch(void* const* d_in, const int* in_sizes, int n_in,
                              void* d_out, int out_size, void* d_ws, size_t ws_size,
                              hipStream_t stream) {
  const float* x = (const float*)d_in[0];
  const float* Wq = (const float*)d_in[1];
  const float* bq = (const float*)d_in[2];
  const float* Wk = (const float*)d_in[3];
  const float* bk = (const float*)d_in[4];
  const float* Wv = (const float*)d_in[5];
  const float* bv = (const float*)d_in[6];
  const float* Wo = (const float*)d_in[7];
  const float* bo = (const float*)d_in[8];
  const float* gamma = (const float*)d_in[9];
  const float* beta = (const float*)d_in[10];

  char* ws = (char*)d_ws;
  const size_t MB = (size_t)1 << 20;
  unsigned short* Xb = (unsigned short*)(ws + 0);        // 8 MB  [4096][1024]
  unsigned short* Wqb = (unsigned short*)(ws + 8 * MB);  // 2 MB
  unsigned short* Wkb = (unsigned short*)(ws + 10 * MB);
  unsigned short* Wvb = (unsigned short*)(ws + 12 * MB);
  unsigned short* Wob = (unsigned short*)(ws + 16 * MB);
  unsigned short* Qb = (unsigned short*)(ws + 18 * MB);   // 8 MB
  unsigned short* Kb = (unsigned short*)(ws + 26 * MB);   // 8 MB
  unsigned short* VTb = (unsigned short*)(ws + 34 * MB);  // 8 MB [1024][4096]
  unsigned short* Ab = (unsigned short*)(ws + 42 * MB);   // 8 MB
  float* proj = (float*)(ws + 0);  // 16 MB, aliases Xb..Wvb after last use

  cvt_all<<<8192, 256, 0, stream>>>(x, Wq, Wk, Wv, Wo, Xb, Wqb, Wkb, Wvb, Wob);

  gemm_qkv<<<dim3(32, 24), 256, 0, stream>>>(Xb, Wqb, Wkb, Wvb, bq, bk, bv, Qb, Kb,
                                             VTb);

  attn_fwd<<<dim3(1024), 256, 0, stream>>>(Qb, Kb, VTb, Ab);

  gemm_o<<<dim3(64, 8), 256, 0, stream>>>(Ab, Wob, bo, x, proj);

  ln_kernel<<<4096, 256, 0, stream>>>(proj, gamma, beta, (float*)d_out);
}

// Round 15
// 146.807 us; speedup vs baseline: 1.0319x; 1.0319x over previous
//
#include <hip/hip_runtime.h>
#include <hip/hip_bf16.h>

typedef float floatx4 __attribute__((ext_vector_type(4)));
typedef short short8 __attribute__((ext_vector_type(8)));

#define S_LEN 4096
#define D_DIM 1024
#define NHEAD 16
#define SCALE_LOG2 0.1803368801111204f  /* 1/sqrt(64) * log2(e) */

__device__ __forceinline__ void gload_lds16(const void* g, void* l) {
  __builtin_amdgcn_global_load_lds(
      (const __attribute__((address_space(1))) unsigned int*)g,
      (__attribute__((address_space(3))) unsigned int*)l, 16, 0, 0);
}

__device__ __forceinline__ unsigned short f2bf_bits(float f) {
  __hip_bfloat16 h = __float2bfloat16(f);
  return __builtin_bit_cast(unsigned short, h);
}

// One launch converts input x (blocks 0..4095) and the 4 weights (4096..8191).
__global__ __launch_bounds__(256) void cvt_all(const float* __restrict__ x,
                                               const float* __restrict__ w0,
                                               const float* __restrict__ w1,
                                               const float* __restrict__ w2,
                                               const float* __restrict__ w3,
                                               unsigned short* __restrict__ xo,
                                               unsigned short* __restrict__ o0,
                                               unsigned short* __restrict__ o1,
                                               unsigned short* __restrict__ o2,
                                               unsigned short* __restrict__ o3) {
  const int bid = blockIdx.x;
  const float* in;
  unsigned short* out;
  int i;
  if (bid < 4096) {
    in = x;
    out = xo;
    i = bid * 256 + threadIdx.x;
  } else {
    const int which = (bid - 4096) >> 10;
    in = which == 0 ? w0 : which == 1 ? w1 : which == 2 ? w2 : w3;
    out = which == 0 ? o0 : which == 1 ? o1 : which == 2 ? o2 : o3;
    i = ((bid - 4096) & 1023) * 256 + threadIdx.x;
  }
  float4 v = reinterpret_cast<const float4*>(in)[i];
  ushort4 u;
  u.x = f2bf_bits(v.x);
  u.y = f2bf_bits(v.y);
  u.z = f2bf_bits(v.z);
  u.w = f2bf_bits(v.w);
  reinterpret_cast<ushort4*>(out)[i] = u;
}

// Fused QKV projection, BK=32, 3-buffer depth-2 staging pipeline with counted
// vmcnt (never drains to 0 mid-loop).  seg = blockIdx.y>>3 picks {Wq,Wk,Wv}.
// seg 0 -> Qb (log2-scaled); seg 1 -> Kb; seg 2 -> VT [1024][4096].
__global__ __launch_bounds__(256) void gemm_qkv(const unsigned short* __restrict__ A,
                                                const unsigned short* __restrict__ WqB,
                                                const unsigned short* __restrict__ WkB,
                                                const unsigned short* __restrict__ WvB,
                                                const float* __restrict__ bq,
                                                const float* __restrict__ bk,
                                                const float* __restrict__ bv,
                                                unsigned short* __restrict__ Qo,
                                                unsigned short* __restrict__ Ko,
                                                unsigned short* __restrict__ VTo) {
  __shared__ __align__(16) unsigned short As[3][128 * 32];
  __shared__ __align__(16) unsigned short Bs[3][128 * 32];
  const int K = 1024, N = 1024, M = 4096;
  const int tid = threadIdx.x;
  const int wave = tid >> 6, lane = tid & 63;
  const int seg = blockIdx.y >> 3;
  const int m0 = blockIdx.x * 128, n0 = (blockIdx.y & 7) * 128;
  const unsigned short* B = seg == 0 ? WqB : seg == 1 ? WkB : WvB;
  const float* bias = seg == 0 ? bq : seg == 1 ? bk : bv;
  const int wr = wave >> 1, wc = wave & 1;

  floatx4 acc[4][4] = {};
  const unsigned short* Ab = A + (size_t)m0 * K;
  const unsigned short* Bb = B + (size_t)n0 * K;
  const int srow = lane >> 2, scol = (lane & 3) * 8;
  const int aRow = lane & 15, kOff = (lane >> 4) * 8;

  // 4 gload_lds per wave per stage (2 A chunks + 2 B chunks)
  auto stage = [&](int buf, int k0) {
#pragma unroll
    for (int i = 0; i < 2; ++i) {
      const int c = wave * 2 + i;
      const int row = c * 16 + srow;
      gload_lds16(Ab + (size_t)row * K + k0 + scol, &As[buf][c * 512]);
      gload_lds16(Bb + (size_t)row * K + k0 + scol, &Bs[buf][c * 512]);
    }
  };

  stage(0, 0);
  stage(1, 32);
  int it = 0;
  for (int k0 = 0; k0 < K; k0 += 32, ++it) {
    const int buf = it % 3;
    if (k0 + 32 < K) {
      // wave's own stage(t) complete; stage(t+1)'s 4 loads may stay in flight
      asm volatile("s_waitcnt vmcnt(4)" ::: "memory");
    } else {
      asm volatile("s_waitcnt vmcnt(0)" ::: "memory");
    }
    __builtin_amdgcn_s_barrier();
    if (k0 + 64 < K) stage((it + 2) % 3, k0 + 64);  // writes buf (t-1)%3: WAR-safe
    short8 af[4], bfg[4];
#pragma unroll
    for (int f = 0; f < 4; ++f) {
      af[f] =
          *reinterpret_cast<const short8*>(&As[buf][(wr * 64 + f * 16 + aRow) * 32 + kOff]);
      bfg[f] =
          *reinterpret_cast<const short8*>(&Bs[buf][(wc * 64 + f * 16 + aRow) * 32 + kOff]);
    }
#pragma unroll
    for (int fm = 0; fm < 4; ++fm)
#pragma unroll
      for (int fn = 0; fn < 4; ++fn)
        acc[fm][fn] =
            __builtin_amdgcn_mfma_f32_16x16x32_bf16(af[fm], bfg[fn], acc[fm][fn], 0, 0, 0);
  }

  const int rb = (lane >> 4) * 4, cl = lane & 15;
  const float osc = seg == 0 ? SCALE_LOG2 : 1.0f;
#pragma unroll
  for (int fm = 0; fm < 4; ++fm)
#pragma unroll
    for (int fn = 0; fn < 4; ++fn)
#pragma unroll
      for (int r = 0; r < 4; ++r) {
        const int row = m0 + wr * 64 + fm * 16 + rb + r;
        const int col = n0 + wc * 64 + fn * 16 + cl;
        const float v = (acc[fm][fn][r] + bias[col]) * osc;
        if (seg == 0)
          Qo[(size_t)row * N + col] = f2bf_bits(v);
        else if (seg == 1)
          Ko[(size_t)row * N + col] = f2bf_bits(v);
        else
          VTo[(size_t)col * M + row] = f2bf_bits(v);
      }
}

// O-projection, BK=32, 3-buffer depth-2 pipeline (3 loads/wave/stage).
// C = A @ Wo^T + bo + resid (f32 out).  Tile 64x128, 512 blocks.
__global__ __launch_bounds__(256) void gemm_o(const unsigned short* __restrict__ A,
                                              const unsigned short* __restrict__ B,
                                              const float* __restrict__ bias,
                                              const float* __restrict__ resid,
                                              float* __restrict__ C) {
  __shared__ __align__(16) unsigned short As[3][64 * 32];
  __shared__ __align__(16) unsigned short Bs[3][128 * 32];
  const int K = 1024, N = 1024;
  const int tid = threadIdx.x;
  const int wave = tid >> 6, lane = tid & 63;
  const int m0 = blockIdx.x * 64, n0 = blockIdx.y * 128;
  const int wr = wave >> 1, wc = wave & 1;

  floatx4 acc[2][4] = {};
  const unsigned short* Ab = A + (size_t)m0 * K;
  const unsigned short* Bb = B + (size_t)n0 * K;
  const int srow = lane >> 2, scol = (lane & 3) * 8;
  const int aRow = lane & 15, kOff = (lane >> 4) * 8;

  auto stage = [&](int buf, int k0) {
#pragma unroll
    for (int i = 0; i < 3; ++i) {
      const int ci = wave * 3 + i;
      if (ci < 4) {
        const int row = ci * 16 + srow;
        gload_lds16(Ab + (size_t)row * K + k0 + scol, &As[buf][ci * 512]);
      } else {
        const int row = (ci - 4) * 16 + srow;
        gload_lds16(Bb + (size_t)row * K + k0 + scol, &Bs[buf][(ci - 4) * 512]);
      }
    }
  };

  stage(0, 0);
  stage(1, 32);
  int it = 0;
  for (int k0 = 0; k0 < K; k0 += 32, ++it) {
    const int buf = it % 3;
    if (k0 + 32 < K) {
      asm volatile("s_waitcnt vmcnt(3)" ::: "memory");
    } else {
      asm volatile("s_waitcnt vmcnt(0)" ::: "memory");
    }
    __builtin_amdgcn_s_barrier();
    if (k0 + 64 < K) stage((it + 2) % 3, k0 + 64);
    short8 af[2], bfg[4];
#pragma unroll
    for (int f = 0; f < 2; ++f)
      af[f] =
          *reinterpret_cast<const short8*>(&As[buf][(wr * 32 + f * 16 + aRow) * 32 + kOff]);
#pragma unroll
    for (int f = 0; f < 4; ++f)
      bfg[f] =
          *reinterpret_cast<const short8*>(&Bs[buf][(wc * 64 + f * 16 + aRow) * 32 + kOff]);
#pragma unroll
    for (int fm = 0; fm < 2; ++fm)
#pragma unroll
      for (int fn = 0; fn < 4; ++fn)
        acc[fm][fn] =
            __builtin_amdgcn_mfma_f32_16x16x32_bf16(af[fm], bfg[fn], acc[fm][fn], 0, 0, 0);
  }

  const int rb = (lane >> 4) * 4, cl = lane & 15;
#pragma unroll
  for (int fm = 0; fm < 2; ++fm)
#pragma unroll
    for (int fn = 0; fn < 4; ++fn)
#pragma unroll
      for (int r = 0; r < 4; ++r) {
        const int row = m0 + wr * 32 + fm * 16 + rb + r;
        const int col = n0 + wc * 64 + fn * 16 + cl;
        C[(size_t)row * N + col] =
            acc[fm][fn][r] + bias[col] + resid[(size_t)row * N + col];
      }
}

// Causal flash attention, swapped-operand, SINGLE barrier per KV tile
// (round-12 structure — best measured: 68.9us, 2.13M conflicts).
// Fixed-m softmax (log2 domain).  Block = 4 waves x 16 q-rows; 1024 blocks
// heaviest-first; LDS 40960B.
__global__ __launch_bounds__(256) void attn_fwd(const unsigned short* __restrict__ Q,
                                                const unsigned short* __restrict__ Kg,
                                                const unsigned short* __restrict__ VT,
                                                unsigned short* __restrict__ O) {
  __shared__ __align__(16) unsigned short Ks[2 * 64 * 64];  // [buf][k][d] swizzled
  __shared__ __align__(16) unsigned short Vs[2 * 64 * 64];  // [buf][d][kv] swizzled
  __shared__ __align__(16) unsigned short Ps[4][16 * 64];   // [wave][q][kv] swizzled

  const int bid = blockIdx.x;
  const int h = bid & 15;
  const int qt = 63 - (bid >> 4);  // heaviest-first
  const int q0 = qt * 64;
  const int wave = threadIdx.x >> 6, lane = threadIdx.x & 63;
  const int l15 = lane & 15, l4 = lane >> 4;
  const int q7 = l15 & 7;

  const int qrow = q0 + wave * 16 + l15;  // this lane's q-row
  short8 qf[2];
#pragma unroll
  for (int ks = 0; ks < 2; ++ks)
    qf[ks] = *reinterpret_cast<const short8*>(
        &Q[(size_t)qrow * D_DIM + h * 64 + ks * 32 + l4 * 8]);

  floatx4 acco[4] = {};  // acco[fn][r]: d = fn*16 + l4*4 + r, q = qrow
  float l_run = 0.f;

  auto stageK = [&](int buf, int t) {
    const int kv0 = t * 64;
#pragma unroll
    for (int i = 0; i < 2; ++i) {
      const int seg = wave * 2 + i;
      const int c = seg * 64 + lane;  // 16B-chunk index in the 64x64 tile
      const int r = c >> 3, jj = c & 7;
      const int sj = (jj ^ (r & 7)) * 8;
      gload_lds16(&Kg[(size_t)(kv0 + r) * D_DIM + h * 64 + sj],
                  &Ks[buf * 4096 + seg * 512]);
    }
  };
  auto stageV = [&](int buf, int t) {
    const int kv0 = t * 64;
#pragma unroll
    for (int i = 0; i < 2; ++i) {
      const int seg = wave * 2 + i;
      const int c = seg * 64 + lane;
      const int r = c >> 3, jj = c & 7;
      const int sj = (jj ^ (r & 7)) * 8;
      gload_lds16(&VT[(size_t)(h * 64 + r) * S_LEN + kv0 + sj],
                  &Vs[buf * 4096 + seg * 512]);
    }
  };

  const int ntiles = qt + 1;
  stageK(0, 0);

  for (int t = 0; t < ntiles; ++t) {
    asm volatile("s_waitcnt vmcnt(0)" ::: "memory");
    __builtin_amdgcn_s_barrier();
    if (t + 1 < ntiles) stageK((t + 1) & 1, t + 1);
    stageV(t & 1, t);

    const unsigned short* ksb = &Ks[(t & 1) * 4096];

    floatx4 accs[4] = {};
#pragma unroll
    for (int ks = 0; ks < 2; ++ks)
#pragma unroll
      for (int fn = 0; fn < 4; ++fn) {
        const int R = fn * 16 + l15;
        const int J = ks * 4 + l4;
        const short8 kf =
            *reinterpret_cast<const short8*>(&ksb[R * 64 + ((J ^ (R & 7)) * 8)]);
        accs[fn] =
            __builtin_amdgcn_mfma_f32_16x16x32_bf16(kf, qf[ks], accs[fn], 0, 0, 0);
      }

    if (t > 0) {
      const unsigned short* vsb = &Vs[((t - 1) & 1) * 4096];
#pragma unroll
      for (int kh = 0; kh < 2; ++kh) {
        const short8 pf = *reinterpret_cast<const short8*>(
            &Ps[wave][l15 * 64 + (((kh * 4 + l4) ^ q7) << 3)]);
#pragma unroll
        for (int fn = 0; fn < 4; ++fn) {
          const int R = fn * 16 + l15;
          const int J = kh * 4 + l4;
          const short8 vf =
              *reinterpret_cast<const short8*>(&vsb[R * 64 + ((J ^ (R & 7)) * 8)]);
          acco[fn] = __builtin_amdgcn_mfma_f32_16x16x32_bf16(vf, pf, acco[fn], 0, 0, 0);
        }
      }
    }

    const int kv0 = t * 64;
    float p[4][4];
    if (t == ntiles - 1) {
#pragma unroll
      for (int fn = 0; fn < 4; ++fn)
#pragma unroll
        for (int r = 0; r < 4; ++r) {
          const int ka = kv0 + fn * 16 + l4 * 4 + r;
          const float s = (ka > qrow) ? -1e30f : accs[fn][r];
          p[fn][r] = __builtin_amdgcn_exp2f(s);
        }
    } else {
#pragma unroll
      for (int fn = 0; fn < 4; ++fn)
#pragma unroll
        for (int r = 0; r < 4; ++r) p[fn][r] = __builtin_amdgcn_exp2f(accs[fn][r]);
    }
    float rs = 0.f;
#pragma unroll
    for (int fn = 0; fn < 4; ++fn)
#pragma unroll
      for (int r = 0; r < 4; ++r) rs += p[fn][r];
    l_run += rs;

#pragma unroll
    for (int fn = 0; fn < 4; ++fn) {
      const int c = 2 * fn + (l4 >> 1);
      const int off = ((c ^ q7) << 3) + ((l4 & 1) << 2);
      uint2 w;
      w.x = (unsigned)f2bf_bits(p[fn][0]) | ((unsigned)f2bf_bits(p[fn][1]) << 16);
      w.y = (unsigned)f2bf_bits(p[fn][2]) | ((unsigned)f2bf_bits(p[fn][3]) << 16);
      *reinterpret_cast<uint2*>(&Ps[wave][l15 * 64 + off]) = w;
    }
  }

  asm volatile("s_waitcnt vmcnt(0)" ::: "memory");
  __builtin_amdgcn_s_barrier();
  {
    const unsigned short* vsb = &Vs[((ntiles - 1) & 1) * 4096];
#pragma unroll
    for (int kh = 0; kh < 2; ++kh) {
      const short8 pf = *reinterpret_cast<const short8*>(
          &Ps[wave][l15 * 64 + (((kh * 4 + l4) ^ q7) << 3)]);
#pragma unroll
      for (int fn = 0; fn < 4; ++fn) {
        const int R = fn * 16 + l15;
        const int J = kh * 4 + l4;
        const short8 vf =
            *reinterpret_cast<const short8*>(&vsb[R * 64 + ((J ^ (R & 7)) * 8)]);
        acco[fn] = __builtin_amdgcn_mfma_f32_16x16x32_bf16(vf, pf, acco[fn], 0, 0, 0);
      }
    }
  }

  l_run += __shfl_xor(l_run, 16);
  l_run += __shfl_xor(l_run, 32);
  const float inv = 1.f / l_run;
#pragma unroll
  for (int fn = 0; fn < 4; ++fn)
#pragma unroll
    for (int rp = 0; rp < 2; ++rp) {
      const unsigned lo = f2bf_bits(acco[fn][2 * rp] * inv);
      const unsigned hi = f2bf_bits(acco[fn][2 * rp + 1] * inv);
      *reinterpret_cast<unsigned*>(
          &O[(size_t)qrow * D_DIM + h * 64 + fn * 16 + l4 * 4 + rp * 2]) =
          lo | (hi << 16);
    }
}

__global__ __launch_bounds__(256) void ln_kernel(const float* __restrict__ X,
                                                 const float* __restrict__ g,
                                                 const float* __restrict__ b,
                                                 float* __restrict__ Y) {
  const int row = blockIdx.x;
  const int t = threadIdx.x;
  const float4 xv = reinterpret_cast<const float4*>(X + (size_t)row * 1024)[t];
  float s = xv.x + xv.y + xv.z + xv.w;
  float s2 = xv.x * xv.x + xv.y * xv.y + xv.z * xv.z + xv.w * xv.w;
#pragma unroll
  for (int off = 1; off < 64; off <<= 1) {
    s += __shfl_xor(s, off);
    s2 += __shfl_xor(s2, off);
  }
  __shared__ float sr[4], sr2[4];
  const int wave = t >> 6, lane = t & 63;
  if (lane == 0) {
    sr[wave] = s;
    sr2[wave] = s2;
  }
  __syncthreads();
  const float S = sr[0] + sr[1] + sr[2] + sr[3];
  const float S2 = sr2[0] + sr2[1] + sr2[2] + sr2[3];
  const float mu = S * (1.f / 1024.f);
  const float var = S2 * (1.f / 1024.f) - mu * mu;
  const float rstd = rsqrtf(var + 1e-5f);
  const float4 gv = reinterpret_cast<const float4*>(g)[t];
  const float4 bv = reinterpret_cast<const float4*>(b)[t];
  float4 y;
  y.x = (xv.x - mu) * rstd * gv.x + bv.x;
  y.y = (xv.y - mu) * rstd * gv.y + bv.y;
  y.z = (xv.z - mu) * rstd * gv.z + bv.z;
  y.w = (xv.w - mu) * rstd * gv.w + bv.w;
  reinterpret_cast<float4*>(Y + (size_t)row * 1024)[t] = y;
}

extern "C" void kernel_launch(void* const* d_in, const int* in_sizes, int n_in,
                              void* d_out, int out_size, void* d_ws, size_t ws_size,
                              hipStream_t stream) {
  const float* x = (const float*)d_in[0];
  const float* Wq = (const float*)d_in[1];
  const float* bq = (const float*)d_in[2];
  const float* Wk = (const float*)d_in[3];
  const float* bk = (const float*)d_in[4];
  const float* Wv = (const float*)d_in[5];
  const float* bv = (const float*)d_in[6];
  const float* Wo = (const float*)d_in[7];
  const float* bo = (const float*)d_in[8];
  const float* gamma = (const float*)d_in[9];
  const float* beta = (const float*)d_in[10];

  char* ws = (char*)d_ws;
  const size_t MB = (size_t)1 << 20;
  unsigned short* Xb = (unsigned short*)(ws + 0);        // 8 MB  [4096][1024]
  unsigned short* Wqb = (unsigned short*)(ws + 8 * MB);  // 2 MB
  unsigned short* Wkb = (unsigned short*)(ws + 10 * MB);
  unsigned short* Wvb = (unsigned short*)(ws + 12 * MB);
  unsigned short* Wob = (unsigned short*)(ws + 16 * MB);
  unsigned short* Qb = (unsigned short*)(ws + 18 * MB);   // 8 MB
  unsigned short* Kb = (unsigned short*)(ws + 26 * MB);   // 8 MB
  unsigned short* VTb = (unsigned short*)(ws + 34 * MB);  // 8 MB [1024][4096]
  unsigned short* Ab = (unsigned short*)(ws + 42 * MB);   // 8 MB
  float* proj = (float*)(ws + 0);  // 16 MB, aliases Xb..Wvb after last use

  cvt_all<<<8192, 256, 0, stream>>>(x, Wq, Wk, Wv, Wo, Xb, Wqb, Wkb, Wvb, Wob);

  gemm_qkv<<<dim3(32, 24), 256, 0, stream>>>(Xb, Wqb, Wkb, Wvb, bq, bk, bv, Qb, Kb,
                                             VTb);

  attn_fwd<<<dim3(1024), 256, 0, stream>>>(Qb, Kb, VTb, Ab);

  gemm_o<<<dim3(64, 8), 256, 0, stream>>>(Ab, Wob, bo, x, proj);

  ln_kernel<<<4096, 256, 0, stream>>>(proj, gamma, beta, (float*)d_out);
}

// Round 16
// 143.778 us; speedup vs baseline: 1.0536x; 1.0211x over previous
//
#include <hip/hip_runtime.h>
#include <hip/hip_bf16.h>

typedef float floatx4 __attribute__((ext_vector_type(4)));
typedef short short8 __attribute__((ext_vector_type(8)));

#define S_LEN 4096
#define D_DIM 1024
#define NHEAD 16
#define SCALE_LOG2 0.1803368801111204f  /* 1/sqrt(64) * log2(e) */

__device__ __forceinline__ void gload_lds16(const void* g, void* l) {
  __builtin_amdgcn_global_load_lds(
      (const __attribute__((address_space(1))) unsigned int*)g,
      (__attribute__((address_space(3))) unsigned int*)l, 16, 0, 0);
}

__device__ __forceinline__ unsigned short f2bf_bits(float f) {
  __hip_bfloat16 h = __float2bfloat16(f);
  return __builtin_bit_cast(unsigned short, h);
}

// One launch converts input x (blocks 0..4095) and the 4 weights (4096..8191).
__global__ __launch_bounds__(256) void cvt_all(const float* __restrict__ x,
                                               const float* __restrict__ w0,
                                               const float* __restrict__ w1,
                                               const float* __restrict__ w2,
                                               const float* __restrict__ w3,
                                               unsigned short* __restrict__ xo,
                                               unsigned short* __restrict__ o0,
                                               unsigned short* __restrict__ o1,
                                               unsigned short* __restrict__ o2,
                                               unsigned short* __restrict__ o3) {
  const int bid = blockIdx.x;
  const float* in;
  unsigned short* out;
  int i;
  if (bid < 4096) {
    in = x;
    out = xo;
    i = bid * 256 + threadIdx.x;
  } else {
    const int which = (bid - 4096) >> 10;
    in = which == 0 ? w0 : which == 1 ? w1 : which == 2 ? w2 : w3;
    out = which == 0 ? o0 : which == 1 ? o1 : which == 2 ? o2 : o3;
    i = ((bid - 4096) & 1023) * 256 + threadIdx.x;
  }
  float4 v = reinterpret_cast<const float4*>(in)[i];
  ushort4 u;
  u.x = f2bf_bits(v.x);
  u.y = f2bf_bits(v.y);
  u.z = f2bf_bits(v.z);
  u.w = f2bf_bits(v.w);
  reinterpret_cast<ushort4*>(out)[i] = u;
}

// Fused QKV projection, BK=32, double-buffered LDS, one barrier per K-step
// (round-12 config — measured best).  seg = blockIdx.y>>3 picks {Wq,Wk,Wv}.
// seg 0 -> Qb (log2-scaled); seg 1 -> Kb; seg 2 -> VT [1024][4096].
__global__ __launch_bounds__(256) void gemm_qkv(const unsigned short* __restrict__ A,
                                                const unsigned short* __restrict__ WqB,
                                                const unsigned short* __restrict__ WkB,
                                                const unsigned short* __restrict__ WvB,
                                                const float* __restrict__ bq,
                                                const float* __restrict__ bk,
                                                const float* __restrict__ bv,
                                                unsigned short* __restrict__ Qo,
                                                unsigned short* __restrict__ Ko,
                                                unsigned short* __restrict__ VTo) {
  __shared__ __align__(16) unsigned short As[2][128 * 32];
  __shared__ __align__(16) unsigned short Bs[2][128 * 32];
  const int K = 1024, N = 1024, M = 4096;
  const int tid = threadIdx.x;
  const int wave = tid >> 6, lane = tid & 63;
  const int seg = blockIdx.y >> 3;
  const int m0 = blockIdx.x * 128, n0 = (blockIdx.y & 7) * 128;
  const unsigned short* B = seg == 0 ? WqB : seg == 1 ? WkB : WvB;
  const float* bias = seg == 0 ? bq : seg == 1 ? bk : bv;
  const int wr = wave >> 1, wc = wave & 1;

  floatx4 acc[4][4] = {};
  const unsigned short* Ab = A + (size_t)m0 * K;
  const unsigned short* Bb = B + (size_t)n0 * K;
  const int srow = lane >> 2, scol = (lane & 3) * 8;
  const int aRow = lane & 15, kOff = (lane >> 4) * 8;

  auto stage = [&](int buf, int k0) {
#pragma unroll
    for (int i = 0; i < 2; ++i) {
      const int c = wave * 2 + i;
      const int row = c * 16 + srow;
      gload_lds16(Ab + (size_t)row * K + k0 + scol, &As[buf][c * 512]);
      gload_lds16(Bb + (size_t)row * K + k0 + scol, &Bs[buf][c * 512]);
    }
  };

  stage(0, 0);
  int buf = 0;
  for (int k0 = 0; k0 < K; k0 += 32, buf ^= 1) {
    asm volatile("s_waitcnt vmcnt(0)" ::: "memory");
    __builtin_amdgcn_s_barrier();
    if (k0 + 32 < K) stage(buf ^ 1, k0 + 32);
    short8 af[4], bfg[4];
#pragma unroll
    for (int f = 0; f < 4; ++f) {
      af[f] =
          *reinterpret_cast<const short8*>(&As[buf][(wr * 64 + f * 16 + aRow) * 32 + kOff]);
      bfg[f] =
          *reinterpret_cast<const short8*>(&Bs[buf][(wc * 64 + f * 16 + aRow) * 32 + kOff]);
    }
#pragma unroll
    for (int fm = 0; fm < 4; ++fm)
#pragma unroll
      for (int fn = 0; fn < 4; ++fn)
        acc[fm][fn] =
            __builtin_amdgcn_mfma_f32_16x16x32_bf16(af[fm], bfg[fn], acc[fm][fn], 0, 0, 0);
  }

  const int rb = (lane >> 4) * 4, cl = lane & 15;
  const float osc = seg == 0 ? SCALE_LOG2 : 1.0f;
#pragma unroll
  for (int fm = 0; fm < 4; ++fm)
#pragma unroll
    for (int fn = 0; fn < 4; ++fn)
#pragma unroll
      for (int r = 0; r < 4; ++r) {
        const int row = m0 + wr * 64 + fm * 16 + rb + r;
        const int col = n0 + wc * 64 + fn * 16 + cl;
        const float v = (acc[fm][fn][r] + bias[col]) * osc;
        if (seg == 0)
          Qo[(size_t)row * N + col] = f2bf_bits(v);
        else if (seg == 1)
          Ko[(size_t)row * N + col] = f2bf_bits(v);
        else
          VTo[(size_t)col * M + row] = f2bf_bits(v);
      }
}

// O-projection, BK=32, double-buffered LDS, one barrier per K-step
// (round-12 config).  C = A @ Wo^T + bo + resid (f32 out).  Tile 64x128.
__global__ __launch_bounds__(256) void gemm_o(const unsigned short* __restrict__ A,
                                              const unsigned short* __restrict__ B,
                                              const float* __restrict__ bias,
                                              const float* __restrict__ resid,
                                              float* __restrict__ C) {
  __shared__ __align__(16) unsigned short As[2][64 * 32];
  __shared__ __align__(16) unsigned short Bs[2][128 * 32];
  const int K = 1024, N = 1024;
  const int tid = threadIdx.x;
  const int wave = tid >> 6, lane = tid & 63;
  const int m0 = blockIdx.x * 64, n0 = blockIdx.y * 128;
  const int wr = wave >> 1, wc = wave & 1;  // wave tile: 32 rows x 64 cols

  floatx4 acc[2][4] = {};
  const unsigned short* Ab = A + (size_t)m0 * K;
  const unsigned short* Bb = B + (size_t)n0 * K;
  const int srow = lane >> 2, scol = (lane & 3) * 8;
  const int aRow = lane & 15, kOff = (lane >> 4) * 8;

  auto stage = [&](int buf, int k0) {
    // 12 chunks (4 A + 8 B), 3 per wave
#pragma unroll
    for (int i = 0; i < 3; ++i) {
      const int ci = wave * 3 + i;
      if (ci < 4) {
        const int row = ci * 16 + srow;
        gload_lds16(Ab + (size_t)row * K + k0 + scol, &As[buf][ci * 512]);
      } else {
        const int row = (ci - 4) * 16 + srow;
        gload_lds16(Bb + (size_t)row * K + k0 + scol, &Bs[buf][(ci - 4) * 512]);
      }
    }
  };

  stage(0, 0);
  int buf = 0;
  for (int k0 = 0; k0 < K; k0 += 32, buf ^= 1) {
    asm volatile("s_waitcnt vmcnt(0)" ::: "memory");
    __builtin_amdgcn_s_barrier();
    if (k0 + 32 < K) stage(buf ^ 1, k0 + 32);
    short8 af[2], bfg[4];
#pragma unroll
    for (int f = 0; f < 2; ++f)
      af[f] =
          *reinterpret_cast<const short8*>(&As[buf][(wr * 32 + f * 16 + aRow) * 32 + kOff]);
#pragma unroll
    for (int f = 0; f < 4; ++f)
      bfg[f] =
          *reinterpret_cast<const short8*>(&Bs[buf][(wc * 64 + f * 16 + aRow) * 32 + kOff]);
#pragma unroll
    for (int fm = 0; fm < 2; ++fm)
#pragma unroll
      for (int fn = 0; fn < 4; ++fn)
        acc[fm][fn] =
            __builtin_amdgcn_mfma_f32_16x16x32_bf16(af[fm], bfg[fn], acc[fm][fn], 0, 0, 0);
  }

  const int rb = (lane >> 4) * 4, cl = lane & 15;
#pragma unroll
  for (int fm = 0; fm < 2; ++fm)
#pragma unroll
    for (int fn = 0; fn < 4; ++fn)
#pragma unroll
      for (int r = 0; r < 4; ++r) {
        const int row = m0 + wr * 32 + fm * 16 + rb + r;
        const int col = n0 + wc * 64 + fn * 16 + cl;
        C[(size_t)row * N + col] =
            acc[fm][fn][r] + bias[col] + resid[(size_t)row * N + col];
      }
}

// Causal flash attention, swapped-operand, SINGLE barrier per KV tile
// (round-12 structure — best measured: 68.9us, 2.13M conflicts).
// Fixed-m softmax (log2 domain).  Block = 4 waves x 16 q-rows; 1024 blocks
// heaviest-first; LDS 40960B.
__global__ __launch_bounds__(256) void attn_fwd(const unsigned short* __restrict__ Q,
                                                const unsigned short* __restrict__ Kg,
                                                const unsigned short* __restrict__ VT,
                                                unsigned short* __restrict__ O) {
  __shared__ __align__(16) unsigned short Ks[2 * 64 * 64];  // [buf][k][d] swizzled
  __shared__ __align__(16) unsigned short Vs[2 * 64 * 64];  // [buf][d][kv] swizzled
  __shared__ __align__(16) unsigned short Ps[4][16 * 64];   // [wave][q][kv] swizzled

  const int bid = blockIdx.x;
  const int h = bid & 15;
  const int qt = 63 - (bid >> 4);  // heaviest-first
  const int q0 = qt * 64;
  const int wave = threadIdx.x >> 6, lane = threadIdx.x & 63;
  const int l15 = lane & 15, l4 = lane >> 4;
  const int q7 = l15 & 7;

  const int qrow = q0 + wave * 16 + l15;  // this lane's q-row
  short8 qf[2];
#pragma unroll
  for (int ks = 0; ks < 2; ++ks)
    qf[ks] = *reinterpret_cast<const short8*>(
        &Q[(size_t)qrow * D_DIM + h * 64 + ks * 32 + l4 * 8]);

  floatx4 acco[4] = {};  // acco[fn][r]: d = fn*16 + l4*4 + r, q = qrow
  float l_run = 0.f;

  auto stageK = [&](int buf, int t) {
    const int kv0 = t * 64;
#pragma unroll
    for (int i = 0; i < 2; ++i) {
      const int seg = wave * 2 + i;
      const int c = seg * 64 + lane;  // 16B-chunk index in the 64x64 tile
      const int r = c >> 3, jj = c & 7;
      const int sj = (jj ^ (r & 7)) * 8;
      gload_lds16(&Kg[(size_t)(kv0 + r) * D_DIM + h * 64 + sj],
                  &Ks[buf * 4096 + seg * 512]);
    }
  };
  auto stageV = [&](int buf, int t) {
    const int kv0 = t * 64;
#pragma unroll
    for (int i = 0; i < 2; ++i) {
      const int seg = wave * 2 + i;
      const int c = seg * 64 + lane;
      const int r = c >> 3, jj = c & 7;
      const int sj = (jj ^ (r & 7)) * 8;
      gload_lds16(&VT[(size_t)(h * 64 + r) * S_LEN + kv0 + sj],
                  &Vs[buf * 4096 + seg * 512]);
    }
  };

  const int ntiles = qt + 1;
  stageK(0, 0);

  for (int t = 0; t < ntiles; ++t) {
    asm volatile("s_waitcnt vmcnt(0)" ::: "memory");
    __builtin_amdgcn_s_barrier();
    if (t + 1 < ntiles) stageK((t + 1) & 1, t + 1);
    stageV(t & 1, t);

    const unsigned short* ksb = &Ks[(t & 1) * 4096];

    floatx4 accs[4] = {};
#pragma unroll
    for (int ks = 0; ks < 2; ++ks)
#pragma unroll
      for (int fn = 0; fn < 4; ++fn) {
        const int R = fn * 16 + l15;
        const int J = ks * 4 + l4;
        const short8 kf =
            *reinterpret_cast<const short8*>(&ksb[R * 64 + ((J ^ (R & 7)) * 8)]);
        accs[fn] =
            __builtin_amdgcn_mfma_f32_16x16x32_bf16(kf, qf[ks], accs[fn], 0, 0, 0);
      }

    if (t > 0) {
      const unsigned short* vsb = &Vs[((t - 1) & 1) * 4096];
#pragma unroll
      for (int kh = 0; kh < 2; ++kh) {
        const short8 pf = *reinterpret_cast<const short8*>(
            &Ps[wave][l15 * 64 + (((kh * 4 + l4) ^ q7) << 3)]);
#pragma unroll
        for (int fn = 0; fn < 4; ++fn) {
          const int R = fn * 16 + l15;
          const int J = kh * 4 + l4;
          const short8 vf =
              *reinterpret_cast<const short8*>(&vsb[R * 64 + ((J ^ (R & 7)) * 8)]);
          acco[fn] = __builtin_amdgcn_mfma_f32_16x16x32_bf16(vf, pf, acco[fn], 0, 0, 0);
        }
      }
    }

    const int kv0 = t * 64;
    float p[4][4];
    if (t == ntiles - 1) {
#pragma unroll
      for (int fn = 0; fn < 4; ++fn)
#pragma unroll
        for (int r = 0; r < 4; ++r) {
          const int ka = kv0 + fn * 16 + l4 * 4 + r;
          const float s = (ka > qrow) ? -1e30f : accs[fn][r];
          p[fn][r] = __builtin_amdgcn_exp2f(s);
        }
    } else {
#pragma unroll
      for (int fn = 0; fn < 4; ++fn)
#pragma unroll
        for (int r = 0; r < 4; ++r) p[fn][r] = __builtin_amdgcn_exp2f(accs[fn][r]);
    }
    float rs = 0.f;
#pragma unroll
    for (int fn = 0; fn < 4; ++fn)
#pragma unroll
      for (int r = 0; r < 4; ++r) rs += p[fn][r];
    l_run += rs;

#pragma unroll
    for (int fn = 0; fn < 4; ++fn) {
      const int c = 2 * fn + (l4 >> 1);
      const int off = ((c ^ q7) << 3) + ((l4 & 1) << 2);
      uint2 w;
      w.x = (unsigned)f2bf_bits(p[fn][0]) | ((unsigned)f2bf_bits(p[fn][1]) << 16);
      w.y = (unsigned)f2bf_bits(p[fn][2]) | ((unsigned)f2bf_bits(p[fn][3]) << 16);
      *reinterpret_cast<uint2*>(&Ps[wave][l15 * 64 + off]) = w;
    }
  }

  asm volatile("s_waitcnt vmcnt(0)" ::: "memory");
  __builtin_amdgcn_s_barrier();
  {
    const unsigned short* vsb = &Vs[((ntiles - 1) & 1) * 4096];
#pragma unroll
    for (int kh = 0; kh < 2; ++kh) {
      const short8 pf = *reinterpret_cast<const short8*>(
          &Ps[wave][l15 * 64 + (((kh * 4 + l4) ^ q7) << 3)]);
#pragma unroll
      for (int fn = 0; fn < 4; ++fn) {
        const int R = fn * 16 + l15;
        const int J = kh * 4 + l4;
        const short8 vf =
            *reinterpret_cast<const short8*>(&vsb[R * 64 + ((J ^ (R & 7)) * 8)]);
        acco[fn] = __builtin_amdgcn_mfma_f32_16x16x32_bf16(vf, pf, acco[fn], 0, 0, 0);
      }
    }
  }

  l_run += __shfl_xor(l_run, 16);
  l_run += __shfl_xor(l_run, 32);
  const float inv = 1.f / l_run;
#pragma unroll
  for (int fn = 0; fn < 4; ++fn)
#pragma unroll
    for (int rp = 0; rp < 2; ++rp) {
      const unsigned lo = f2bf_bits(acco[fn][2 * rp] * inv);
      const unsigned hi = f2bf_bits(acco[fn][2 * rp + 1] * inv);
      *reinterpret_cast<unsigned*>(
          &O[(size_t)qrow * D_DIM + h * 64 + fn * 16 + l4 * 4 + rp * 2]) =
          lo | (hi << 16);
    }
}

__global__ __launch_bounds__(256) void ln_kernel(const float* __restrict__ X,
                                                 const float* __restrict__ g,
                                                 const float* __restrict__ b,
                                                 float* __restrict__ Y) {
  const int row = blockIdx.x;
  const int t = threadIdx.x;
  const float4 xv = reinterpret_cast<const float4*>(X + (size_t)row * 1024)[t];
  float s = xv.x + xv.y + xv.z + xv.w;
  float s2 = xv.x * xv.x + xv.y * xv.y + xv.z * xv.z + xv.w * xv.w;
#pragma unroll
  for (int off = 1; off < 64; off <<= 1) {
    s += __shfl_xor(s, off);
    s2 += __shfl_xor(s2, off);
  }
  __shared__ float sr[4], sr2[4];
  const int wave = t >> 6, lane = t & 63;
  if (lane == 0) {
    sr[wave] = s;
    sr2[wave] = s2;
  }
  __syncthreads();
  const float S = sr[0] + sr[1] + sr[2] + sr[3];
  const float S2 = sr2[0] + sr2[1] + sr2[2] + sr2[3];
  const float mu = S * (1.f / 1024.f);
  const float var = S2 * (1.f / 1024.f) - mu * mu;
  const float rstd = rsqrtf(var + 1e-5f);
  const float4 gv = reinterpret_cast<const float4*>(g)[t];
  const float4 bv = reinterpret_cast<const float4*>(b)[t];
  float4 y;
  y.x = (xv.x - mu) * rstd * gv.x + bv.x;
  y.y = (xv.y - mu) * rstd * gv.y + bv.y;
  y.z = (xv.z - mu) * rstd * gv.z + bv.z;
  y.w = (xv.w - mu) * rstd * gv.w + bv.w;
  reinterpret_cast<float4*>(Y + (size_t)row * 1024)[t] = y;
}

extern "C" void kernel_launch(void* const* d_in, const int* in_sizes, int n_in,
                              void* d_out, int out_size, void* d_ws, size_t ws_size,
                              hipStream_t stream) {
  const float* x = (const float*)d_in[0];
  const float* Wq = (const float*)d_in[1];
  const float* bq = (const float*)d_in[2];
  const float* Wk = (const float*)d_in[3];
  const float* bk = (const float*)d_in[4];
  const float* Wv = (const float*)d_in[5];
  const float* bv = (const float*)d_in[6];
  const float* Wo = (const float*)d_in[7];
  const float* bo = (const float*)d_in[8];
  const float* gamma = (const float*)d_in[9];
  const float* beta = (const float*)d_in[10];

  char* ws = (char*)d_ws;
  const size_t MB = (size_t)1 << 20;
  unsigned short* Xb = (unsigned short*)(ws + 0);        // 8 MB  [4096][1024]
  unsigned short* Wqb = (unsigned short*)(ws + 8 * MB);  // 2 MB
  unsigned short* Wkb = (unsigned short*)(ws + 10 * MB);
  unsigned short* Wvb = (unsigned short*)(ws + 12 * MB);
  unsigned short* Wob = (unsigned short*)(ws + 16 * MB);
  unsigned short* Qb = (unsigned short*)(ws + 18 * MB);   // 8 MB
  unsigned short* Kb = (unsigned short*)(ws + 26 * MB);   // 8 MB
  unsigned short* VTb = (unsigned short*)(ws + 34 * MB);  // 8 MB [1024][4096]
  unsigned short* Ab = (unsigned short*)(ws + 42 * MB);   // 8 MB
  float* proj = (float*)(ws + 0);  // 16 MB, aliases Xb..Wvb after last use

  cvt_all<<<8192, 256, 0, stream>>>(x, Wq, Wk, Wv, Wo, Xb, Wqb, Wkb, Wvb, Wob);

  gemm_qkv<<<dim3(32, 24), 256, 0, stream>>>(Xb, Wqb, Wkb, Wvb, bq, bk, bv, Qb, Kb,
                                             VTb);

  attn_fwd<<<dim3(1024), 256, 0, stream>>>(Qb, Kb, VTb, Ab);

  gemm_o<<<dim3(64, 8), 256, 0, stream>>>(Ab, Wob, bo, x, proj);

  ln_kernel<<<4096, 256, 0, stream>>>(proj, gamma, beta, (float*)d_out);
}

// Round 17
// 141.989 us; speedup vs baseline: 1.0669x; 1.0126x over previous
//
#include <hip/hip_runtime.h>
#include <hip/hip_bf16.h>

typedef float floatx4 __attribute__((ext_vector_type(4)));
typedef short short8 __attribute__((ext_vector_type(8)));

#define S_LEN 4096
#define D_DIM 1024
#define NHEAD 16
#define SCALE_LOG2 0.1803368801111204f  /* 1/sqrt(64) * log2(e) */

__device__ __forceinline__ void gload_lds16(const void* g, void* l) {
  __builtin_amdgcn_global_load_lds(
      (const __attribute__((address_space(1))) unsigned int*)g,
      (__attribute__((address_space(3))) unsigned int*)l, 16, 0, 0);
}

__device__ __forceinline__ unsigned short f2bf_bits(float f) {
  __hip_bfloat16 h = __float2bfloat16(f);
  return __builtin_bit_cast(unsigned short, h);
}

__device__ __forceinline__ float bf2f(unsigned short u) {
  unsigned v = (unsigned)u << 16;
  return __builtin_bit_cast(float, v);
}

// One launch converts input x (blocks 0..4095) and the 4 weights (4096..8191).
__global__ __launch_bounds__(256) void cvt_all(const float* __restrict__ x,
                                               const float* __restrict__ w0,
                                               const float* __restrict__ w1,
                                               const float* __restrict__ w2,
                                               const float* __restrict__ w3,
                                               unsigned short* __restrict__ xo,
                                               unsigned short* __restrict__ o0,
                                               unsigned short* __restrict__ o1,
                                               unsigned short* __restrict__ o2,
                                               unsigned short* __restrict__ o3) {
  const int bid = blockIdx.x;
  const float* in;
  unsigned short* out;
  int i;
  if (bid < 4096) {
    in = x;
    out = xo;
    i = bid * 256 + threadIdx.x;
  } else {
    const int which = (bid - 4096) >> 10;
    in = which == 0 ? w0 : which == 1 ? w1 : which == 2 ? w2 : w3;
    out = which == 0 ? o0 : which == 1 ? o1 : which == 2 ? o2 : o3;
    i = ((bid - 4096) & 1023) * 256 + threadIdx.x;
  }
  float4 v = reinterpret_cast<const float4*>(in)[i];
  ushort4 u;
  u.x = f2bf_bits(v.x);
  u.y = f2bf_bits(v.y);
  u.z = f2bf_bits(v.z);
  u.w = f2bf_bits(v.w);
  reinterpret_cast<ushort4*>(out)[i] = u;
}

// Fused QKV projection, BK=32, double-buffered LDS, one barrier per K-step
// (round-12 config — measured best).  seg = blockIdx.y>>3 picks {Wq,Wk,Wv}.
// seg 0 -> Qb (log2-scaled); seg 1 -> Kb; seg 2 -> VT [1024][4096].
__global__ __launch_bounds__(256) void gemm_qkv(const unsigned short* __restrict__ A,
                                                const unsigned short* __restrict__ WqB,
                                                const unsigned short* __restrict__ WkB,
                                                const unsigned short* __restrict__ WvB,
                                                const float* __restrict__ bq,
                                                const float* __restrict__ bk,
                                                const float* __restrict__ bv,
                                                unsigned short* __restrict__ Qo,
                                                unsigned short* __restrict__ Ko,
                                                unsigned short* __restrict__ VTo) {
  __shared__ __align__(16) unsigned short As[2][128 * 32];
  __shared__ __align__(16) unsigned short Bs[2][128 * 32];
  const int K = 1024, N = 1024, M = 4096;
  const int tid = threadIdx.x;
  const int wave = tid >> 6, lane = tid & 63;
  const int seg = blockIdx.y >> 3;
  const int m0 = blockIdx.x * 128, n0 = (blockIdx.y & 7) * 128;
  const unsigned short* B = seg == 0 ? WqB : seg == 1 ? WkB : WvB;
  const float* bias = seg == 0 ? bq : seg == 1 ? bk : bv;
  const int wr = wave >> 1, wc = wave & 1;

  floatx4 acc[4][4] = {};
  const unsigned short* Ab = A + (size_t)m0 * K;
  const unsigned short* Bb = B + (size_t)n0 * K;
  const int srow = lane >> 2, scol = (lane & 3) * 8;
  const int aRow = lane & 15, kOff = (lane >> 4) * 8;

  auto stage = [&](int buf, int k0) {
#pragma unroll
    for (int i = 0; i < 2; ++i) {
      const int c = wave * 2 + i;
      const int row = c * 16 + srow;
      gload_lds16(Ab + (size_t)row * K + k0 + scol, &As[buf][c * 512]);
      gload_lds16(Bb + (size_t)row * K + k0 + scol, &Bs[buf][c * 512]);
    }
  };

  stage(0, 0);
  int buf = 0;
  for (int k0 = 0; k0 < K; k0 += 32, buf ^= 1) {
    asm volatile("s_waitcnt vmcnt(0)" ::: "memory");
    __builtin_amdgcn_s_barrier();
    if (k0 + 32 < K) stage(buf ^ 1, k0 + 32);
    short8 af[4], bfg[4];
#pragma unroll
    for (int f = 0; f < 4; ++f) {
      af[f] =
          *reinterpret_cast<const short8*>(&As[buf][(wr * 64 + f * 16 + aRow) * 32 + kOff]);
      bfg[f] =
          *reinterpret_cast<const short8*>(&Bs[buf][(wc * 64 + f * 16 + aRow) * 32 + kOff]);
    }
#pragma unroll
    for (int fm = 0; fm < 4; ++fm)
#pragma unroll
      for (int fn = 0; fn < 4; ++fn)
        acc[fm][fn] =
            __builtin_amdgcn_mfma_f32_16x16x32_bf16(af[fm], bfg[fn], acc[fm][fn], 0, 0, 0);
  }

  const int rb = (lane >> 4) * 4, cl = lane & 15;
  const float osc = seg == 0 ? SCALE_LOG2 : 1.0f;
#pragma unroll
  for (int fm = 0; fm < 4; ++fm)
#pragma unroll
    for (int fn = 0; fn < 4; ++fn)
#pragma unroll
      for (int r = 0; r < 4; ++r) {
        const int row = m0 + wr * 64 + fm * 16 + rb + r;
        const int col = n0 + wc * 64 + fn * 16 + cl;
        const float v = (acc[fm][fn][r] + bias[col]) * osc;
        if (seg == 0)
          Qo[(size_t)row * N + col] = f2bf_bits(v);
        else if (seg == 1)
          Ko[(size_t)row * N + col] = f2bf_bits(v);
        else
          VTo[(size_t)col * M + row] = f2bf_bits(v);
      }
}

// O-projection, BK=32, double-buffered LDS, one barrier per K-step.
// C = A @ Wo^T + bo + resid, output bf16 (halves proj write + LN read traffic).
__global__ __launch_bounds__(256) void gemm_o(const unsigned short* __restrict__ A,
                                              const unsigned short* __restrict__ B,
                                              const float* __restrict__ bias,
                                              const float* __restrict__ resid,
                                              unsigned short* __restrict__ C) {
  __shared__ __align__(16) unsigned short As[2][64 * 32];
  __shared__ __align__(16) unsigned short Bs[2][128 * 32];
  const int K = 1024, N = 1024;
  const int tid = threadIdx.x;
  const int wave = tid >> 6, lane = tid & 63;
  const int m0 = blockIdx.x * 64, n0 = blockIdx.y * 128;
  const int wr = wave >> 1, wc = wave & 1;  // wave tile: 32 rows x 64 cols

  floatx4 acc[2][4] = {};
  const unsigned short* Ab = A + (size_t)m0 * K;
  const unsigned short* Bb = B + (size_t)n0 * K;
  const int srow = lane >> 2, scol = (lane & 3) * 8;
  const int aRow = lane & 15, kOff = (lane >> 4) * 8;

  auto stage = [&](int buf, int k0) {
    // 12 chunks (4 A + 8 B), 3 per wave
#pragma unroll
    for (int i = 0; i < 3; ++i) {
      const int ci = wave * 3 + i;
      if (ci < 4) {
        const int row = ci * 16 + srow;
        gload_lds16(Ab + (size_t)row * K + k0 + scol, &As[buf][ci * 512]);
      } else {
        const int row = (ci - 4) * 16 + srow;
        gload_lds16(Bb + (size_t)row * K + k0 + scol, &Bs[buf][(ci - 4) * 512]);
      }
    }
  };

  stage(0, 0);
  int buf = 0;
  for (int k0 = 0; k0 < K; k0 += 32, buf ^= 1) {
    asm volatile("s_waitcnt vmcnt(0)" ::: "memory");
    __builtin_amdgcn_s_barrier();
    if (k0 + 32 < K) stage(buf ^ 1, k0 + 32);
    short8 af[2], bfg[4];
#pragma unroll
    for (int f = 0; f < 2; ++f)
      af[f] =
          *reinterpret_cast<const short8*>(&As[buf][(wr * 32 + f * 16 + aRow) * 32 + kOff]);
#pragma unroll
    for (int f = 0; f < 4; ++f)
      bfg[f] =
          *reinterpret_cast<const short8*>(&Bs[buf][(wc * 64 + f * 16 + aRow) * 32 + kOff]);
#pragma unroll
    for (int fm = 0; fm < 2; ++fm)
#pragma unroll
      for (int fn = 0; fn < 4; ++fn)
        acc[fm][fn] =
            __builtin_amdgcn_mfma_f32_16x16x32_bf16(af[fm], bfg[fn], acc[fm][fn], 0, 0, 0);
  }

  const int rb = (lane >> 4) * 4, cl = lane & 15;
#pragma unroll
  for (int fm = 0; fm < 2; ++fm)
#pragma unroll
    for (int fn = 0; fn < 4; ++fn)
#pragma unroll
      for (int r = 0; r < 4; ++r) {
        const int row = m0 + wr * 32 + fm * 16 + rb + r;
        const int col = n0 + wc * 64 + fn * 16 + cl;
        const float v = acc[fm][fn][r] + bias[col] + resid[(size_t)row * N + col];
        C[(size_t)row * N + col] = f2bf_bits(v);
      }
}

// Causal flash attention, swapped-operand, SINGLE barrier per KV tile
// (round-12 structure — best measured: 68.9us, 2.13M conflicts).
// Fixed-m softmax (log2 domain).  Block = 4 waves x 16 q-rows; 1024 blocks
// heaviest-first; LDS 40960B.
__global__ __launch_bounds__(256) void attn_fwd(const unsigned short* __restrict__ Q,
                                                const unsigned short* __restrict__ Kg,
                                                const unsigned short* __restrict__ VT,
                                                unsigned short* __restrict__ O) {
  __shared__ __align__(16) unsigned short Ks[2 * 64 * 64];  // [buf][k][d] swizzled
  __shared__ __align__(16) unsigned short Vs[2 * 64 * 64];  // [buf][d][kv] swizzled
  __shared__ __align__(16) unsigned short Ps[4][16 * 64];   // [wave][q][kv] swizzled

  const int bid = blockIdx.x;
  const int h = bid & 15;
  const int qt = 63 - (bid >> 4);  // heaviest-first
  const int q0 = qt * 64;
  const int wave = threadIdx.x >> 6, lane = threadIdx.x & 63;
  const int l15 = lane & 15, l4 = lane >> 4;
  const int q7 = l15 & 7;

  const int qrow = q0 + wave * 16 + l15;  // this lane's q-row
  short8 qf[2];
#pragma unroll
  for (int ks = 0; ks < 2; ++ks)
    qf[ks] = *reinterpret_cast<const short8*>(
        &Q[(size_t)qrow * D_DIM + h * 64 + ks * 32 + l4 * 8]);

  floatx4 acco[4] = {};  // acco[fn][r]: d = fn*16 + l4*4 + r, q = qrow
  float l_run = 0.f;

  auto stageK = [&](int buf, int t) {
    const int kv0 = t * 64;
#pragma unroll
    for (int i = 0; i < 2; ++i) {
      const int seg = wave * 2 + i;
      const int c = seg * 64 + lane;  // 16B-chunk index in the 64x64 tile
      const int r = c >> 3, jj = c & 7;
      const int sj = (jj ^ (r & 7)) * 8;
      gload_lds16(&Kg[(size_t)(kv0 + r) * D_DIM + h * 64 + sj],
                  &Ks[buf * 4096 + seg * 512]);
    }
  };
  auto stageV = [&](int buf, int t) {
    const int kv0 = t * 64;
#pragma unroll
    for (int i = 0; i < 2; ++i) {
      const int seg = wave * 2 + i;
      const int c = seg * 64 + lane;
      const int r = c >> 3, jj = c & 7;
      const int sj = (jj ^ (r & 7)) * 8;
      gload_lds16(&VT[(size_t)(h * 64 + r) * S_LEN + kv0 + sj],
                  &Vs[buf * 4096 + seg * 512]);
    }
  };

  const int ntiles = qt + 1;
  stageK(0, 0);

  for (int t = 0; t < ntiles; ++t) {
    asm volatile("s_waitcnt vmcnt(0)" ::: "memory");
    __builtin_amdgcn_s_barrier();
    if (t + 1 < ntiles) stageK((t + 1) & 1, t + 1);
    stageV(t & 1, t);

    const unsigned short* ksb = &Ks[(t & 1) * 4096];

    floatx4 accs[4] = {};
#pragma unroll
    for (int ks = 0; ks < 2; ++ks)
#pragma unroll
      for (int fn = 0; fn < 4; ++fn) {
        const int R = fn * 16 + l15;
        const int J = ks * 4 + l4;
        const short8 kf =
            *reinterpret_cast<const short8*>(&ksb[R * 64 + ((J ^ (R & 7)) * 8)]);
        accs[fn] =
            __builtin_amdgcn_mfma_f32_16x16x32_bf16(kf, qf[ks], accs[fn], 0, 0, 0);
      }

    if (t > 0) {
      const unsigned short* vsb = &Vs[((t - 1) & 1) * 4096];
#pragma unroll
      for (int kh = 0; kh < 2; ++kh) {
        const short8 pf = *reinterpret_cast<const short8*>(
            &Ps[wave][l15 * 64 + (((kh * 4 + l4) ^ q7) << 3)]);
#pragma unroll
        for (int fn = 0; fn < 4; ++fn) {
          const int R = fn * 16 + l15;
          const int J = kh * 4 + l4;
          const short8 vf =
              *reinterpret_cast<const short8*>(&vsb[R * 64 + ((J ^ (R & 7)) * 8)]);
          acco[fn] = __builtin_amdgcn_mfma_f32_16x16x32_bf16(vf, pf, acco[fn], 0, 0, 0);
        }
      }
    }

    const int kv0 = t * 64;
    float p[4][4];
    if (t == ntiles - 1) {
#pragma unroll
      for (int fn = 0; fn < 4; ++fn)
#pragma unroll
        for (int r = 0; r < 4; ++r) {
          const int ka = kv0 + fn * 16 + l4 * 4 + r;
          const float s = (ka > qrow) ? -1e30f : accs[fn][r];
          p[fn][r] = __builtin_amdgcn_exp2f(s);
        }
    } else {
#pragma unroll
      for (int fn = 0; fn < 4; ++fn)
#pragma unroll
        for (int r = 0; r < 4; ++r) p[fn][r] = __builtin_amdgcn_exp2f(accs[fn][r]);
    }
    float rs = 0.f;
#pragma unroll
    for (int fn = 0; fn < 4; ++fn)
#pragma unroll
      for (int r = 0; r < 4; ++r) rs += p[fn][r];
    l_run += rs;

#pragma unroll
    for (int fn = 0; fn < 4; ++fn) {
      const int c = 2 * fn + (l4 >> 1);
      const int off = ((c ^ q7) << 3) + ((l4 & 1) << 2);
      uint2 w;
      w.x = (unsigned)f2bf_bits(p[fn][0]) | ((unsigned)f2bf_bits(p[fn][1]) << 16);
      w.y = (unsigned)f2bf_bits(p[fn][2]) | ((unsigned)f2bf_bits(p[fn][3]) << 16);
      *reinterpret_cast<uint2*>(&Ps[wave][l15 * 64 + off]) = w;
    }
  }

  asm volatile("s_waitcnt vmcnt(0)" ::: "memory");
  __builtin_amdgcn_s_barrier();
  {
    const unsigned short* vsb = &Vs[((ntiles - 1) & 1) * 4096];
#pragma unroll
    for (int kh = 0; kh < 2; ++kh) {
      const short8 pf = *reinterpret_cast<const short8*>(
          &Ps[wave][l15 * 64 + (((kh * 4 + l4) ^ q7) << 3)]);
#pragma unroll
      for (int fn = 0; fn < 4; ++fn) {
        const int R = fn * 16 + l15;
        const int J = kh * 4 + l4;
        const short8 vf =
            *reinterpret_cast<const short8*>(&vsb[R * 64 + ((J ^ (R & 7)) * 8)]);
        acco[fn] = __builtin_amdgcn_mfma_f32_16x16x32_bf16(vf, pf, acco[fn], 0, 0, 0);
      }
    }
  }

  l_run += __shfl_xor(l_run, 16);
  l_run += __shfl_xor(l_run, 32);
  const float inv = 1.f / l_run;
#pragma unroll
  for (int fn = 0; fn < 4; ++fn)
#pragma unroll
    for (int rp = 0; rp < 2; ++rp) {
      const unsigned lo = f2bf_bits(acco[fn][2 * rp] * inv);
      const unsigned hi = f2bf_bits(acco[fn][2 * rp + 1] * inv);
      *reinterpret_cast<unsigned*>(
          &O[(size_t)qrow * D_DIM + h * 64 + fn * 16 + l4 * 4 + rp * 2]) =
          lo | (hi << 16);
    }
}

// LayerNorm over bf16 proj rows (stats in f32), f32 output.
__global__ __launch_bounds__(256) void ln_kernel(const unsigned short* __restrict__ X,
                                                 const float* __restrict__ g,
                                                 const float* __restrict__ b,
                                                 float* __restrict__ Y) {
  const int row = blockIdx.x;
  const int t = threadIdx.x;
  const ushort4 xu = reinterpret_cast<const ushort4*>(X + (size_t)row * 1024)[t];
  float x0 = bf2f(xu.x), x1 = bf2f(xu.y), x2 = bf2f(xu.z), x3 = bf2f(xu.w);
  float s = x0 + x1 + x2 + x3;
  float s2 = x0 * x0 + x1 * x1 + x2 * x2 + x3 * x3;
#pragma unroll
  for (int off = 1; off < 64; off <<= 1) {
    s += __shfl_xor(s, off);
    s2 += __shfl_xor(s2, off);
  }
  __shared__ float sr[4], sr2[4];
  const int wave = t >> 6, lane = t & 63;
  if (lane == 0) {
    sr[wave] = s;
    sr2[wave] = s2;
  }
  __syncthreads();
  const float S = sr[0] + sr[1] + sr[2] + sr[3];
  const float S2 = sr2[0] + sr2[1] + sr2[2] + sr2[3];
  const float mu = S * (1.f / 1024.f);
  const float var = S2 * (1.f / 1024.f) - mu * mu;
  const float rstd = rsqrtf(var + 1e-5f);
  const float4 gv = reinterpret_cast<const float4*>(g)[t];
  const float4 bv = reinterpret_cast<const float4*>(b)[t];
  float4 y;
  y.x = (x0 - mu) * rstd * gv.x + bv.x;
  y.y = (x1 - mu) * rstd * gv.y + bv.y;
  y.z = (x2 - mu) * rstd * gv.z + bv.z;
  y.w = (x3 - mu) * rstd * gv.w + bv.w;
  reinterpret_cast<float4*>(Y + (size_t)row * 1024)[t] = y;
}

extern "C" void kernel_launch(void* const* d_in, const int* in_sizes, int n_in,
                              void* d_out, int out_size, void* d_ws, size_t ws_size,
                              hipStream_t stream) {
  const float* x = (const float*)d_in[0];
  const float* Wq = (const float*)d_in[1];
  const float* bq = (const float*)d_in[2];
  const float* Wk = (const float*)d_in[3];
  const float* bk = (const float*)d_in[4];
  const float* Wv = (const float*)d_in[5];
  const float* bv = (const float*)d_in[6];
  const float* Wo = (const float*)d_in[7];
  const float* bo = (const float*)d_in[8];
  const float* gamma = (const float*)d_in[9];
  const float* beta = (const float*)d_in[10];

  char* ws = (char*)d_ws;
  const size_t MB = (size_t)1 << 20;
  unsigned short* Xb = (unsigned short*)(ws + 0);        // 8 MB  [4096][1024]
  unsigned short* Wqb = (unsigned short*)(ws + 8 * MB);  // 2 MB
  unsigned short* Wkb = (unsigned short*)(ws + 10 * MB);
  unsigned short* Wvb = (unsigned short*)(ws + 12 * MB);
  unsigned short* Wob = (unsigned short*)(ws + 16 * MB);
  unsigned short* Qb = (unsigned short*)(ws + 18 * MB);   // 8 MB
  unsigned short* Kb = (unsigned short*)(ws + 26 * MB);   // 8 MB
  unsigned short* VTb = (unsigned short*)(ws + 34 * MB);  // 8 MB [1024][4096]
  unsigned short* Ab = (unsigned short*)(ws + 42 * MB);   // 8 MB
  unsigned short* proj = (unsigned short*)(ws + 50 * MB);  // 8 MB bf16

  cvt_all<<<8192, 256, 0, stream>>>(x, Wq, Wk, Wv, Wo, Xb, Wqb, Wkb, Wvb, Wob);

  gemm_qkv<<<dim3(32, 24), 256, 0, stream>>>(Xb, Wqb, Wkb, Wvb, bq, bk, bv, Qb, Kb,
                                             VTb);

  attn_fwd<<<dim3(1024), 256, 0, stream>>>(Qb, Kb, VTb, Ab);

  gemm_o<<<dim3(64, 8), 256, 0, stream>>>(Ab, Wob, bo, x, proj);

  ln_kernel<<<4096, 256, 0, stream>>>(proj, gamma, beta, (float*)d_out);
}